// Round 5
// baseline (221.741 us; speedup 1.0000x reference)
//
#include <hip/hip_runtime.h>

// Problem constants
#define CCH   640        // channels
#define WIN   19         // input spatial width
#define NWp   5          // pooled width
#define P     25         // NW*NW
#define BSn   100        // B*S
#define BSC   64000      // BSn*CCH slices per tensor
#define META_ELEMS 3200000
#define SLICE_F 361               // 19*19
#define WGRP_SL 4                 // slices per group (5776 B, 16B-aligned)
#define WGRP_F  (WGRP_SL * SLICE_F)   // 1444 floats
#define WGRP_V4 361               // float4s per group
#define NWG_PER_TENSOR (BSC / WGRP_SL)   // 16000
#define NWG_TOTAL (2 * NWG_PER_TENSOR)   // 32000
#define POOL_BLOCKS 768           // 3 blocks/CU (LDS-capped), persistent
#define POOL_WAVES  (POOL_BLOCKS * 4)    // 3072

// Async global->LDS DMA, 16 B/lane. LDS dest = wave-uniform base + lane*16.
__device__ __forceinline__ void gload16(const float* g, float* l) {
  __builtin_amdgcn_global_load_lds(
      (const __attribute__((address_space(1))) void*)g,
      (__attribute__((address_space(3))) void*)l, 16, 0, 0);
}

__device__ __forceinline__ void issue_grp(const float* __restrict__ sup,
                                          const float* __restrict__ qry,
                                          int grp, int lane, float* buf) {
  const int which = (grp >= NWG_PER_TENSOR) ? 1 : 0;
  const int g = which ? grp - NWG_PER_TENSOR : grp;
  const float* __restrict__ src = (which ? qry : sup) + (size_t)g * WGRP_F;
#pragma unroll
  for (int i = 0; i < 6; ++i) {
    const int v = i * 64 + lane;              // float4 index
    if (v < WGRP_V4) gload16(src + v * 4, buf + i * 256);
  }
}

__device__ __forceinline__ void compute_grp(int grp, int lane,
                                            const float* __restrict__ lt,
                                            float* __restrict__ out) {
  const int which = (grp >= NWG_PER_TENSOR) ? 1 : 0;
  const int g = which ? grp - NWG_PER_TENSOR : grp;
  const int slice0 = g * WGRP_SL;
  for (int o = lane; o < WGRP_SL * P; o += 64) {   // 100 outputs per group
    const int s = o / P, p = o - s * P;
    const int i = p / NWp, j = p - i * NWp;
    const int r0 = (i * WIN) / NWp, r1 = ((i + 1) * WIN + NWp - 1) / NWp;
    const int c0 = (j * WIN) / NWp, c1 = ((j + 1) * WIN + NWp - 1) / NWp;
    const float* __restrict__ tb = lt + s * SLICE_F;
    float sum = 0.f;
    for (int r = r0; r < r1; ++r)
#pragma unroll
      for (int c = 0; c < 5; ++c) {                // max bin width is 5
        if (c0 + c < c1) sum += tb[r * WIN + c0 + c];
      }
    const float val = sum / (float)((r1 - r0) * (c1 - c0));
    const int rem = slice0 + s;
    const int bs = rem / CCH, cch = rem - bs * CCH;
    out[((size_t)bs * (2 * CCH) + which * CCH + cch) * P + p] = val;
  }
}

// ---------------------------------------------------------------------------
// Kernel 1: adaptive avg pool, persistent waves, per-wave double-buffered
// global_load_lds pipeline. While computing group k, the next group's 6 DMAs
// are already in flight (s_waitcnt vmcnt(6) leaves them pending). No
// __syncthreads; each wave owns a private 2x5776B LDS region.
// ---------------------------------------------------------------------------
__global__ __launch_bounds__(256) void pool_kernel(
    const float* __restrict__ sup, const float* __restrict__ qry,
    float* __restrict__ out) {
  __shared__ __align__(16) float tile[4][2][WGRP_F];   // 46208 B/block
  const int lane = threadIdx.x & 63;
  const int wave = threadIdx.x >> 6;
  const int wid = blockIdx.x * 4 + wave;               // [0, 3072)
  float* const buf0 = &tile[wave][0][0];
  float* const buf1 = &tile[wave][1][0];

  int grp = wid;
  if (grp < NWG_TOTAL) issue_grp(sup, qry, grp, lane, buf0);
  int k = 0;
  for (; grp < NWG_TOTAL; grp += POOL_WAVES, ++k) {
    float* const cur = (k & 1) ? buf1 : buf0;
    float* const nxt = (k & 1) ? buf0 : buf1;
    const int ngrp = grp + POOL_WAVES;
    if (ngrp < NWG_TOTAL) {
      issue_grp(sup, qry, ngrp, lane, nxt);
      __builtin_amdgcn_wave_barrier();
      __builtin_amdgcn_s_waitcnt(0x0F76);   // vmcnt(6): cur buffer complete,
      __builtin_amdgcn_wave_barrier();      // next 6 DMAs stay in flight
    } else {
      __builtin_amdgcn_wave_barrier();
      __builtin_amdgcn_s_waitcnt(0x0F70);   // vmcnt(0): final group
      __builtin_amdgcn_wave_barrier();
    }
    compute_grp(grp, lane, cur, out);
  }
}

// ---------------------------------------------------------------------------
// Kernel 2a: partial dots/norms per (bs, 128-channel chunk). 500 blocks.
// ---------------------------------------------------------------------------
#define CHUNK 128
#define CP_FLOATS (CHUNK * P)             // 3200 floats per buffer
#define CP_INSTS  13                      // ceil(3200 / 256)
__global__ __launch_bounds__(640) void cos_part(
    const float* __restrict__ meta, float* __restrict__ dpart,
    float* __restrict__ spart, float* __restrict__ qpart) {
  __shared__ __align__(16) float ls[CP_FLOATS];
  __shared__ __align__(16) float lq[CP_FLOATS];
  const int t = threadIdx.x;
  const int lane = t & 63, wave = t >> 6;  // 10 waves
  const int blk = blockIdx.x;              // bs*5 + ch
  const int bs = blk / 5, ch = blk - bs * 5;
  const float* __restrict__ sb = meta + (size_t)bs * (2 * CCH * P) + ch * CP_FLOATS;
  const float* __restrict__ qb = sb + CCH * P;

  for (int i = wave; i < 2 * CP_INSTS; i += 10) {
    const int isq = (i >= CP_INSTS);
    const int ii = isq ? i - CP_INSTS : i;
    const int f = ii * 256 + lane * 4;
    if (f < CP_FLOATS)
      gload16((isq ? qb : sb) + f, (isq ? lq : ls) + ii * 256);
  }
  __syncthreads();

  if (t < P * P) {
    const int p = t / P, q = t - p * P;
    float dot = 0.f;
#pragma unroll 8
    for (int k = 0; k < CHUNK; ++k)
      dot = fmaf(ls[k * P + p], lq[k * P + q], dot);
    dpart[(size_t)blk * (P * P) + t] = dot;
  }
  if (t < P) {
    float n = 0.f;
#pragma unroll 8
    for (int k = 0; k < CHUNK; ++k) { float v = ls[k * P + t]; n = fmaf(v, v, n); }
    spart[blk * P + t] = n;
  } else if (t >= 32 && t < 32 + P) {
    const int q = t - 32;
    float n = 0.f;
#pragma unroll 8
    for (int k = 0; k < CHUNK; ++k) { float v = lq[k * P + q]; n = fmaf(v, v, n); }
    qpart[blk * P + q] = n;
  }
}

// ---------------------------------------------------------------------------
// Kernel 2b: reduce 5 partials, normalize, max over query positions.
// ---------------------------------------------------------------------------
__global__ __launch_bounds__(640) void cos_final(
    const float* __restrict__ dpart, const float* __restrict__ spart,
    const float* __restrict__ qpart, float* __restrict__ out) {
  __shared__ float sn[P], qn[P], simbuf[P * P];
  const int t = threadIdx.x, bs = blockIdx.x;
  if (t < P) {
    float a = 0.f;
#pragma unroll
    for (int ch = 0; ch < 5; ++ch) a += spart[(bs * 5 + ch) * P + t];
    sn[t] = sqrtf(a);
  } else if (t >= 32 && t < 32 + P) {
    const int q = t - 32;
    float a = 0.f;
#pragma unroll
    for (int ch = 0; ch < 5; ++ch) a += qpart[(bs * 5 + ch) * P + q];
    qn[q] = sqrtf(a);
  }
  __syncthreads();
  if (t < P * P) {
    const int p = t / P, q = t - p * P;
    float d = 0.f;
#pragma unroll
    for (int ch = 0; ch < 5; ++ch) d += dpart[(size_t)(bs * 5 + ch) * (P * P) + t];
    simbuf[t] = d / fmaxf(sn[p] * qn[q], 1e-8f);
  }
  __syncthreads();
  if (t < P) {
    float m = simbuf[t * P];
#pragma unroll
    for (int k = 1; k < P; ++k) m = fmaxf(m, simbuf[t * P + k]);
    out[META_ELEMS + bs * P + t] = m;
  }
}

extern "C" void kernel_launch(void* const* d_in, const int* in_sizes, int n_in,
                              void* d_out, int out_size, void* d_ws, size_t ws_size,
                              hipStream_t stream) {
  const float* sup = (const float*)d_in[0];
  const float* qry = (const float*)d_in[1];
  float* out = (float*)d_out;

  // Workspace layout (floats): dpart[500*625], spart[500*25], qpart[500*25]
  float* dpart = (float*)d_ws;
  float* spart = dpart + 500 * (P * P);
  float* qpart = spart + 500 * P;

  pool_kernel<<<POOL_BLOCKS, 256, 0, stream>>>(sup, qry, out);
  cos_part<<<BSn * 5, 640, 0, stream>>>(out, dpart, spart, qpart);
  cos_final<<<BSn, 640, 0, stream>>>(dpart, spart, qpart, out);
}

// Round 6
// 215.324 us; speedup vs baseline: 1.0298x; 1.0298x over previous
//
#include <hip/hip_runtime.h>

// Problem constants
#define CCH   640        // channels
#define WIN   19         // input spatial width
#define NWp   5          // pooled width
#define P     25         // NW*NW
#define BSn   100        // B*S
#define META_ELEMS 3200000
#define SLICE_F 361      // 19*19
#define CHUNK 128        // channels per block
#define NCH   5          // chunks per bs
#define WG_SL 4          // slices per wave per staging round
#define WG_F  (WG_SL * SLICE_F)   // 1444 floats = 5776 B (16B-aligned: slice0 % 4 == 0)
#define WG_V4 361        // float4s per round

// Async global->LDS DMA, 16 B/lane. LDS dest = wave-uniform base + lane*16.
__device__ __forceinline__ void gload16(const float* g, float* l) {
  __builtin_amdgcn_global_load_lds(
      (const __attribute__((address_space(1))) void*)g,
      (__attribute__((address_space(3))) void*)l, 16, 0, 0);
}

// ---------------------------------------------------------------------------
// Fused kernel: block = (bs, 128-channel chunk). Pools 128 support + 128
// query slices (wave-autonomous global_load_lds staging, vmcnt-only waits),
// writes meta region of d_out, keeps pooled values in LDS, then computes
// partial dots (625 pairs over 128 ch) + partial norms into workspace.
// Eliminates the meta readback and the separate cos_part launch; dot phase
// of one block overlaps staging latency of co-resident blocks.
// ---------------------------------------------------------------------------
__global__ __launch_bounds__(256) void fused_kernel(
    const float* __restrict__ sup, const float* __restrict__ qry,
    float* __restrict__ out, float* __restrict__ dpart,
    float* __restrict__ spart, float* __restrict__ qpart) {
  __shared__ __align__(16) float tile[4][WG_F];   // 23104 B staging (wave-private)
  __shared__ float ps[CHUNK * P];                 // pooled support [c][p], 12.8 KB
  __shared__ float pq[CHUNK * P];                 // pooled query   [c][p], 12.8 KB
  const int t = threadIdx.x;
  const int lane = t & 63;
  const int wave = t >> 6;
  const int blk = blockIdx.x;                     // bs*5 + ch
  const int bs = blk / NCH, ch = blk - bs * NCH;
  float* const lt = &tile[wave][0];

  // 16 staging+pool rounds per wave: 8 support halves, 8 query halves.
  for (int half = 0; half < 2; ++half) {
    const float* __restrict__ srcT = half ? qry : sup;
    float* __restrict__ plds = half ? pq : ps;
    for (int it = 0; it < 8; ++it) {
      // Drain this wave's outstanding ds_reads before DMA overwrites tile.
      __builtin_amdgcn_wave_barrier();
      __builtin_amdgcn_s_waitcnt(0xC07F);         // lgkmcnt(0) only
      __builtin_amdgcn_wave_barrier();

      const int lc0 = it * 16 + wave * 4;         // local channel base [0,128)
      const float* __restrict__ src =
          srcT + (size_t)(bs * CCH + ch * CHUNK + lc0) * SLICE_F;
#pragma unroll
      for (int i = 0; i < 6; ++i) {
        const int v = i * 64 + lane;              // float4 index
        if (v < WG_V4) gload16(src + v * 4, lt + i * 256);
      }
      __builtin_amdgcn_wave_barrier();
      __builtin_amdgcn_s_waitcnt(0x0F70);         // vmcnt(0) only
      __builtin_amdgcn_wave_barrier();

      for (int o = lane; o < WG_SL * P; o += 64) {   // 100 outputs per round
        const int s = o / P, p = o - s * P;
        const int i = p / NWp, j = p - i * NWp;
        const int r0 = (i * WIN) / NWp, r1 = ((i + 1) * WIN + NWp - 1) / NWp;
        const int c0 = (j * WIN) / NWp, c1 = ((j + 1) * WIN + NWp - 1) / NWp;
        const float* __restrict__ tb = lt + s * SLICE_F;
        float sum = 0.f;
        for (int r = r0; r < r1; ++r)
#pragma unroll
          for (int c = 0; c < 5; ++c) {              // max bin width is 5
            if (c0 + c < c1) sum += tb[r * WIN + c0 + c];
          }
        const float val = sum / (float)((r1 - r0) * (c1 - c0));
        const int cglob = ch * CHUNK + lc0 + s;      // channel within [0,640)
        out[((size_t)bs * (2 * CCH) + half * CCH + cglob) * P + p] = val;
        plds[(lc0 + s) * P + p] = val;
      }
    }
  }
  __syncthreads();

  // Partial norms (sum of squares over this chunk's 128 channels).
  if (t < P) {
    float n = 0.f;
#pragma unroll 8
    for (int k = 0; k < CHUNK; ++k) { float v = ps[k * P + t]; n = fmaf(v, v, n); }
    spart[blk * P + t] = n;
  } else if (t >= 32 && t < 32 + P) {
    const int q = t - 32;
    float n = 0.f;
#pragma unroll 8
    for (int k = 0; k < CHUNK; ++k) { float v = pq[k * P + q]; n = fmaf(v, v, n); }
    qpart[blk * P + q] = n;
  }

  // Partial dots: 625 pairs over 256 threads (2-3 pairs each).
  for (int pair = t; pair < P * P; pair += 256) {
    const int p = pair / P, q = pair - p * P;
    float dot = 0.f;
#pragma unroll 8
    for (int k = 0; k < CHUNK; ++k)
      dot = fmaf(ps[k * P + p], pq[k * P + q], dot);
    dpart[(size_t)blk * (P * P) + pair] = dot;
  }
}

// ---------------------------------------------------------------------------
// Final: reduce 5 chunk-partials, normalize, max over query positions.
// ---------------------------------------------------------------------------
__global__ __launch_bounds__(640) void cos_final(
    const float* __restrict__ dpart, const float* __restrict__ spart,
    const float* __restrict__ qpart, float* __restrict__ out) {
  __shared__ float sn[P], qn[P], simbuf[P * P];
  const int t = threadIdx.x, bs = blockIdx.x;
  if (t < P) {
    float a = 0.f;
#pragma unroll
    for (int ch = 0; ch < NCH; ++ch) a += spart[(bs * NCH + ch) * P + t];
    sn[t] = sqrtf(a);
  } else if (t >= 32 && t < 32 + P) {
    const int q = t - 32;
    float a = 0.f;
#pragma unroll
    for (int ch = 0; ch < NCH; ++ch) a += qpart[(bs * NCH + ch) * P + q];
    qn[q] = sqrtf(a);
  }
  __syncthreads();
  if (t < P * P) {
    const int p = t / P, q = t - p * P;
    float d = 0.f;
#pragma unroll
    for (int ch = 0; ch < NCH; ++ch) d += dpart[(size_t)(bs * NCH + ch) * (P * P) + t];
    simbuf[t] = d / fmaxf(sn[p] * qn[q], 1e-8f);
  }
  __syncthreads();
  if (t < P) {
    float m = simbuf[t * P];
#pragma unroll
    for (int k = 1; k < P; ++k) m = fmaxf(m, simbuf[t * P + k]);
    out[META_ELEMS + bs * P + t] = m;
  }
}

extern "C" void kernel_launch(void* const* d_in, const int* in_sizes, int n_in,
                              void* d_out, int out_size, void* d_ws, size_t ws_size,
                              hipStream_t stream) {
  const float* sup = (const float*)d_in[0];
  const float* qry = (const float*)d_in[1];
  float* out = (float*)d_out;

  // Workspace (floats): dpart[500*625], spart[500*25], qpart[500*25]
  float* dpart = (float*)d_ws;
  float* spart = dpart + 500 * (P * P);
  float* qpart = spart + 500 * P;

  fused_kernel<<<BSn * NCH, 256, 0, stream>>>(sup, qry, out, dpart, spart, qpart);
  cos_final<<<BSn, 640, 0, stream>>>(dpart, spart, qpart, out);
}

// Round 8
// 196.576 us; speedup vs baseline: 1.1280x; 1.0954x over previous
//
#include <hip/hip_runtime.h>

// Problem constants
#define CCH   640        // channels
#define WIN   19         // input spatial width
#define NWp   5          // pooled width
#define P     25         // NW*NW
#define BSn   100        // B*S
#define BSC   64000      // BSn*CCH slices per tensor
#define META_ELEMS 3200000
#define SLICE_F 361      // 19*19
#define WGRP_SL 4        // slices per wave (5776 B, 16B-aligned)
#define WGRP_F  (WGRP_SL * SLICE_F)   // 1444 floats
#define WGRP_V4 361      // float4s per wave-group
#define NWG_PER_TENSOR (BSC / WGRP_SL)   // 16000
#define NWG_TOTAL (2 * NWG_PER_TENSOR)   // 32000

// Native vector type (HIP_vector_type is a struct — rejected by
// __builtin_nontemporal_load; ext_vector_type is accepted).
typedef float floatx4 __attribute__((ext_vector_type(4)));

// ---------------------------------------------------------------------------
// Kernel 1: adaptive avg pool. Wave-autonomous: each wave stages its private
// 4-slice group via NONTEMPORAL float4 loads (bypass L1 allocation — testing
// the L1-outstanding-miss wall) -> b128 LDS writes -> pool -> coalesced store.
// No barriers; LDS region is wave-private; compiler inserts within-wave
// vmcnt/lgkmcnt waits.
// ---------------------------------------------------------------------------
__global__ __launch_bounds__(256) void pool_kernel(
    const float* __restrict__ sup, const float* __restrict__ qry,
    float* __restrict__ out) {
  __shared__ __align__(16) float tile[4][WGRP_F];   // 23104 B, wave-private quarters
  const int lane = threadIdx.x & 63;
  const int wave = threadIdx.x >> 6;
  const int wg = blockIdx.x * 4 + wave;             // [0, 32000)
  const int which = (wg >= NWG_PER_TENSOR) ? 1 : 0;
  const int g = which ? wg - NWG_PER_TENSOR : wg;
  const float* __restrict__ src = (which ? qry : sup) + (size_t)g * WGRP_F;
  float* __restrict__ lt = &tile[wave][0];

  // Stage 1444 floats: 6 nontemporal float4 loads per lane (last partial).
  floatx4 v[6];
#pragma unroll
  for (int i = 0; i < 6; ++i) {
    const int idx = i * 64 + lane;
    if (idx < WGRP_V4)
      v[i] = __builtin_nontemporal_load((const floatx4*)src + idx);
  }
#pragma unroll
  for (int i = 0; i < 6; ++i) {
    const int idx = i * 64 + lane;
    if (idx < WGRP_V4) *(floatx4*)(lt + idx * 4) = v[i];
  }

  // Pool: 100 outputs per wave-group.
  const int slice0 = g * WGRP_SL;
  for (int o = lane; o < WGRP_SL * P; o += 64) {
    const int s = o / P, p = o - s * P;
    const int i = p / NWp, j = p - i * NWp;
    const int r0 = (i * WIN) / NWp, r1 = ((i + 1) * WIN + NWp - 1) / NWp;
    const int c0 = (j * WIN) / NWp, c1 = ((j + 1) * WIN + NWp - 1) / NWp;
    const float* __restrict__ tb = lt + s * SLICE_F;
    float sum = 0.f;
    for (int r = r0; r < r1; ++r)
#pragma unroll
      for (int c = 0; c < 5; ++c) {                 // max bin width is 5
        if (c0 + c < c1) sum += tb[r * WIN + c0 + c];
      }
    const float val = sum / (float)((r1 - r0) * (c1 - c0));
    const int rem = slice0 + s;
    const int bs = rem / CCH, cch = rem - bs * CCH;
    out[((size_t)bs * (2 * CCH) + which * CCH + cch) * P + p] = val;
  }
}

// ---------------------------------------------------------------------------
// Kernel 2a: partial dots/norms per (bs, 128-channel chunk). 500 blocks.
// Transposed padded LDS layout [p][c] (row stride 132 floats, 16B-aligned)
// so the dot loop uses float4 LDS reads: 2x32 ds_read_b128 per pair instead
// of 2x128 scalar ds_read_b32.
// ---------------------------------------------------------------------------
#define CHUNK 128
#define ROWS  132                         // CHUNK + 4 pad
__global__ __launch_bounds__(640) void cos_part(
    const float* __restrict__ meta, float* __restrict__ dpart,
    float* __restrict__ spart, float* __restrict__ qpart) {
  __shared__ __align__(16) float ls[P * ROWS];
  __shared__ __align__(16) float lq[P * ROWS];
  const int t = threadIdx.x;
  const int blk = blockIdx.x;              // bs*5 + ch
  const int bs = blk / 5, ch = blk - bs * 5;
  const float* __restrict__ sb = meta + (size_t)bs * (2 * CCH * P) + ch * (CHUNK * P);
  const float* __restrict__ qb = sb + CCH * P;

  // Load coalesced from global [c][p], transpose-scatter into LDS [p][c].
  for (int idx = t; idx < CHUNK * P; idx += 640) {
    const int c = idx / P, p = idx - c * P;
    ls[p * ROWS + c] = sb[idx];
    lq[p * ROWS + c] = qb[idx];
  }
  __syncthreads();

  if (t < P * P) {
    const int p = t / P, q = t - p * P;
    const floatx4* __restrict__ ap = (const floatx4*)(ls + p * ROWS);
    const floatx4* __restrict__ bq = (const floatx4*)(lq + q * ROWS);
    floatx4 acc = {0.f, 0.f, 0.f, 0.f};
#pragma unroll 8
    for (int k = 0; k < CHUNK / 4; ++k) {
      const floatx4 a = ap[k], b = bq[k];
      acc.x = fmaf(a.x, b.x, acc.x);
      acc.y = fmaf(a.y, b.y, acc.y);
      acc.z = fmaf(a.z, b.z, acc.z);
      acc.w = fmaf(a.w, b.w, acc.w);
    }
    dpart[(size_t)blk * (P * P) + t] = (acc.x + acc.y) + (acc.z + acc.w);
  }
  if (t < P) {
    const floatx4* __restrict__ ap = (const floatx4*)(ls + t * ROWS);
    floatx4 acc = {0.f, 0.f, 0.f, 0.f};
#pragma unroll 8
    for (int k = 0; k < CHUNK / 4; ++k) {
      const floatx4 a = ap[k];
      acc.x = fmaf(a.x, a.x, acc.x);
      acc.y = fmaf(a.y, a.y, acc.y);
      acc.z = fmaf(a.z, a.z, acc.z);
      acc.w = fmaf(a.w, a.w, acc.w);
    }
    spart[blk * P + t] = (acc.x + acc.y) + (acc.z + acc.w);
  } else if (t >= 32 && t < 32 + P) {
    const int q = t - 32;
    const floatx4* __restrict__ bq = (const floatx4*)(lq + q * ROWS);
    floatx4 acc = {0.f, 0.f, 0.f, 0.f};
#pragma unroll 8
    for (int k = 0; k < CHUNK / 4; ++k) {
      const floatx4 b = bq[k];
      acc.x = fmaf(b.x, b.x, acc.x);
      acc.y = fmaf(b.y, b.y, acc.y);
      acc.z = fmaf(b.z, b.z, acc.z);
      acc.w = fmaf(b.w, b.w, acc.w);
    }
    qpart[blk * P + q] = (acc.x + acc.y) + (acc.z + acc.w);
  }
}

// ---------------------------------------------------------------------------
// Kernel 2b: reduce 5 partials, normalize, max over query positions.
// ---------------------------------------------------------------------------
__global__ __launch_bounds__(640) void cos_final(
    const float* __restrict__ dpart, const float* __restrict__ spart,
    const float* __restrict__ qpart, float* __restrict__ out) {
  __shared__ float sn[P], qn[P], simbuf[P * P];
  const int t = threadIdx.x, bs = blockIdx.x;
  if (t < P) {
    float a = 0.f;
#pragma unroll
    for (int ch = 0; ch < 5; ++ch) a += spart[(bs * 5 + ch) * P + t];
    sn[t] = sqrtf(a);
  } else if (t >= 32 && t < 32 + P) {
    const int q = t - 32;
    float a = 0.f;
#pragma unroll
    for (int ch = 0; ch < 5; ++ch) a += qpart[(bs * 5 + ch) * P + q];
    qn[q] = sqrtf(a);
  }
  __syncthreads();
  if (t < P * P) {
    const int p = t / P, q = t - p * P;
    float d = 0.f;
#pragma unroll
    for (int ch = 0; ch < 5; ++ch) d += dpart[(size_t)(bs * 5 + ch) * (P * P) + t];
    simbuf[t] = d / fmaxf(sn[p] * qn[q], 1e-8f);
  }
  __syncthreads();
  if (t < P) {
    float m = simbuf[t * P];
#pragma unroll
    for (int k = 1; k < P; ++k) m = fmaxf(m, simbuf[t * P + k]);
    out[META_ELEMS + bs * P + t] = m;
  }
}

extern "C" void kernel_launch(void* const* d_in, const int* in_sizes, int n_in,
                              void* d_out, int out_size, void* d_ws, size_t ws_size,
                              hipStream_t stream) {
  const float* sup = (const float*)d_in[0];
  const float* qry = (const float*)d_in[1];
  float* out = (float*)d_out;

  // Workspace (floats): dpart[500*625], spart[500*25], qpart[500*25]
  float* dpart = (float*)d_ws;
  float* spart = dpart + 500 * (P * P);
  float* qpart = spart + 500 * P;

  pool_kernel<<<NWG_TOTAL / 4, 256, 0, stream>>>(sup, qry, out);
  cos_part<<<BSn * 5, 640, 0, stream>>>(out, dpart, spart, qpart);
  cos_final<<<BSn, 640, 0, stream>>>(dpart, spart, qpart, out);
}